// Round 12
// baseline (216.869 us; speedup 1.0000x reference)
//
#include <hip/hip_runtime.h>
#include <stdint.h>

#define SLEN 2048
#define EDIM 1024
#define NH 16
#define HD 64
#define QLD 1152   // qkv packed row: [q 0..1023 | k 1024..1087 | v 1088..1151]

typedef unsigned short u16;
typedef short bf8 __attribute__((ext_vector_type(8)));   // 8 bf16 in 4 VGPRs
typedef float f4 __attribute__((ext_vector_type(4)));
typedef bf8 bf8_a __attribute__((may_alias));
typedef uint2 uint2_a __attribute__((may_alias));
typedef uint4 uint4_a __attribute__((may_alias));
typedef float4 float4_a __attribute__((may_alias));

__device__ __forceinline__ float bf2f(u16 u) {
  union { unsigned u; float f; } c; c.u = ((unsigned)u) << 16; return c.f;
}
__device__ __forceinline__ u16 f2bf(float x) {
  union { __bf16 h; u16 u; } c; c.h = (__bf16)x; return c.u;  // HW cvt, RNE
}
__device__ __forceinline__ unsigned pk2bf(float a, float b) {
  union { __bf16 h[2]; unsigned u; } c;
  c.h[0] = (__bf16)a; c.h[1] = (__bf16)b;
  return c.u;
}
__device__ __forceinline__ void async_cp16(u16* lds, const u16* g) {
  __builtin_amdgcn_global_load_lds((__attribute__((address_space(1))) void*)g,
                                   (__attribute__((address_space(3))) void*)lds,
                                   16, 0, 0);
}

// ---------------- prep: weight transposes + bias -----------------------------
__device__ __forceinline__ void tcvt_tile(const float* src, int srcLd,
                                          u16* dst, int dstLd, int r0, int c0) {
  __shared__ u16 tile[64][65];
  const int t = threadIdx.x;
#pragma unroll
  for (int i = 0; i < 16; ++i) {
    int e = i * 256 + t, rr = e >> 6, cc = e & 63;
    tile[rr][cc] = f2bf(src[(size_t)(r0 + rr) * srcLd + c0 + cc]);
  }
  __syncthreads();
#pragma unroll
  for (int i = 0; i < 16; ++i) {
    int e = i * 256 + t, j = e >> 6, ii = e & 63;
    dst[(size_t)(c0 + j) * dstLd + r0 + ii] = tile[ii][j];
  }
}

__global__ void prep_w(const float* wq, const float* wk, const float* wv,
                       const float* wo, const float* bq, const float* bk,
                       const float* bv, const float* bo,
                       u16* wT, u16* woT, float* bQKV, float* bOut) {
  const int yy = blockIdx.y;
  if (yy < 16) tcvt_tile(wq, 1024, wT, 1024, blockIdx.x * 64, yy * 64);
  else if (yy < 32) tcvt_tile(wo, 1024, woT, 1024, blockIdx.x * 64, (yy - 16) * 64);
  else if (yy == 32) tcvt_tile(wk, 64, wT + (size_t)1024 * 1024, 1024, blockIdx.x * 64, 0);
  else if (yy == 33) tcvt_tile(wv, 64, wT + (size_t)1088 * 1024, 1024, blockIdx.x * 64, 0);
  else {
    int i = blockIdx.x * 256 + threadIdx.x;
    if (i < 1024) bQKV[i] = bq[i];
    else if (i < 1088) bQKV[i] = bk[i - 1024];
    else if (i < 1152) bQKV[i] = bv[i - 1088];
    int j = i - 1152;
    if (j >= 0 && j < 1024) bOut[j] = bo[j];
  }
}

// ---------------- QKV GEMM: A = x (fp32, converted in staging) ---------------
// C[4096][QLD] = bf16(x) @ wT^T + bQKV; V cols also scattered to vT[b][d][s].
// 64x128 tile, XOR chunk swizzle (chunk c of row m at slot m*8 + ((c+m)&7)).
__global__ __launch_bounds__(256) void gemm_qkv(
    const float* __restrict__ X, const u16* __restrict__ Bt,
    const float* __restrict__ bias, u16* __restrict__ C,
    u16* __restrict__ vtb) {
  __shared__ __align__(16) u16 As[64 * 64];
  __shared__ __align__(16) u16 Bs[128 * 64];
  const int K = 1024;
  const int tn0 = blockIdx.x * 128, tm0 = blockIdx.y * 64;
  const int tid = threadIdx.x, wave = tid >> 6, lane = tid & 63;
  const int quad = lane >> 4, l16 = lane & 15;
  const int wm = wave & 1, wn = wave >> 1;

  f4 acc[2][4];
#pragma unroll
  for (int i = 0; i < 2; ++i)
#pragma unroll
    for (int j = 0; j < 4; ++j) acc[i][j] = f4{0.f, 0.f, 0.f, 0.f};

  int aslot[2], bslot[4]; size_t aoff[2], boff[4];
#pragma unroll
  for (int i = 0; i < 2; ++i) {
    int s = i * 256 + tid, m = s >> 3, kc = s & 7, c = (kc - m) & 7;
    aslot[i] = s; aoff[i] = (size_t)(tm0 + m) * K + c * 8;
  }
#pragma unroll
  for (int i = 0; i < 4; ++i) {
    int s = i * 256 + tid, n = s >> 3, kc = s & 7, c = (kc - n) & 7;
    bslot[i] = s; boff[i] = (size_t)(tn0 + n) * K + c * 8;
  }
  int ard[2][2], brd[4][2];
#pragma unroll
  for (int mi = 0; mi < 2; ++mi) {
    int m = wm * 32 + mi * 16 + l16;
#pragma unroll
    for (int kk = 0; kk < 2; ++kk)
      ard[mi][kk] = (m * 8 + (((kk * 4 + quad) + m) & 7)) * 8;
  }
#pragma unroll
  for (int ni = 0; ni < 4; ++ni) {
    int n = wn * 64 + ni * 16 + l16;
#pragma unroll
    for (int kk = 0; kk < 2; ++kk)
      brd[ni][kk] = (n * 8 + (((kk * 4 + quad) + n) & 7)) * 8;
  }

  for (int it = 0; it < 16; ++it) {
    const size_t kb = (size_t)it * 64;
    // A: fp32 loads + convert (pre-barrier, regs only)
    uint4 staged[2];
#pragma unroll
    for (int i = 0; i < 2; ++i) {
      float4 f0 = *(const float4_a*)(X + aoff[i] + kb);
      float4 f1 = *(const float4_a*)(X + aoff[i] + kb + 4);
      staged[i].x = pk2bf(f0.x, f0.y);
      staged[i].y = pk2bf(f0.z, f0.w);
      staged[i].z = pk2bf(f1.x, f1.y);
      staged[i].w = pk2bf(f1.z, f1.w);
    }
    __syncthreads();  // prior frag reads done
#pragma unroll
    for (int i = 0; i < 2; ++i) *(uint4_a*)&As[aslot[i] * 8] = staged[i];
#pragma unroll
    for (int i = 0; i < 4; ++i) async_cp16(&Bs[bslot[i] * 8], Bt + boff[i] + kb);
    __syncthreads();  // drains lgkm+vmcnt -> staged data visible
#pragma unroll
    for (int kk = 0; kk < 2; ++kk) {
      bf8 af[2], bfr[4];
#pragma unroll
      for (int mi = 0; mi < 2; ++mi) af[mi] = *(const bf8_a*)&As[ard[mi][kk]];
#pragma unroll
      for (int ni = 0; ni < 4; ++ni) bfr[ni] = *(const bf8_a*)&Bs[brd[ni][kk]];
#pragma unroll
      for (int mi = 0; mi < 2; ++mi)
#pragma unroll
        for (int ni = 0; ni < 4; ++ni)
          acc[mi][ni] = __builtin_amdgcn_mfma_f32_16x16x32_bf16(
              af[mi], bfr[ni], acc[mi][ni], 0, 0, 0);
    }
  }

  float bv[4];
#pragma unroll
  for (int ni = 0; ni < 4; ++ni) bv[ni] = bias[tn0 + wn * 64 + ni * 16 + l16];
#pragma unroll
  for (int mi = 0; mi < 2; ++mi) {
    int row0 = tm0 + wm * 32 + mi * 16 + quad * 4;
#pragma unroll
    for (int ni = 0; ni < 4; ++ni) {
      int col = tn0 + wn * 64 + ni * 16 + l16;
      float vv[4];
#pragma unroll
      for (int r = 0; r < 4; ++r) vv[r] = acc[mi][ni][r] + bv[ni];
#pragma unroll
      for (int r = 0; r < 4; ++r)
        C[(size_t)(row0 + r) * QLD + col] = f2bf(vv[r]);
      if (col >= 1088) {
        int d = col - 1088, bb = row0 >> 11, s0 = row0 & 2047;
        uint2 pk;
        pk.x = pk2bf(vv[0], vv[1]);
        pk.y = pk2bf(vv[2], vv[3]);
        *(uint2_a*)&vtb[(size_t)(bb * 64 + d) * SLEN + s0] = pk;
      }
    }
  }
}

// ---------------- flash attention (MQA), split-K, 128-thr blocks -------------
// Grid (32 qt64, 32 bh, 2 ks) = 2048 blocks; LDS 20KB -> 8 blocks/CU.
// 2 waves x 32 q-rows; 64-key k-tiles; fragment-major Kf/Vf; wave-private Ps.
// No-max softmax partials (additive): O unnormalized bf16 + l fp32.
__global__ __launch_bounds__(128, 6) void attn_kernel(
    const u16* __restrict__ qkv, const u16* __restrict__ vT,
    u16* __restrict__ Opart, float* __restrict__ lpart) {
  __shared__ __align__(16) u16 Kf[4096];    // 64 keys x 64 d, frag-major
  __shared__ __align__(16) u16 Vf[4096];    // 64 d x 64 keys, frag-major
  __shared__ __align__(16) u16 Ps[2048];    // 2 waves x 1024 (one 32-key group)
  const int qt = blockIdx.x, bh = blockIdx.y, ks = blockIdx.z;
  const int b = bh >> 4, h = bh & 15;
  const int tid = threadIdx.x, wave = tid >> 6, lane = tid & 63;
  const int quad = lane >> 4, l16 = lane & 15;

  // Q prologue: 64 rows x 64 = 512 chunks, [kk:1][g:2][qd:2][r16:4];
  // kk=0 half in Kf, kk=1 half in Vf.
#pragma unroll
  for (int i = 0; i < 4; ++i) {
    int d = i * 128 + tid;
    int kk = d >> 8, g = (d >> 6) & 3, qd = (d >> 4) & 3, r16 = d & 15;
    u16* dst = (kk == 0) ? &Kf[d * 8] : &Vf[(d - 256) * 8];
    async_cp16(dst, qkv + (size_t)(b * SLEN + qt * 64 + g * 16 + r16) * QLD +
                        h * HD + (kk * 4 + qd) * 8);
  }
  __syncthreads();
  bf8 bq[2][2];  // [nt][kk]: B-frag rows wave*32 + nt*16 + l16
#pragma unroll
  for (int nt = 0; nt < 2; ++nt) {
    bq[nt][0] = *(const bf8_a*)&Kf[((wave * 2 + nt) * 64 + lane) * 8];
    bq[nt][1] = *(const bf8_a*)&Vf[((wave * 2 + nt) * 64 + lane) * 8];
  }

  f4 acc_o[2][4];
#pragma unroll
  for (int i = 0; i < 2; ++i)
#pragma unroll
    for (int j = 0; j < 4; ++j) acc_o[i][j] = f4{0.f, 0.f, 0.f, 0.f};
  f4 lr4[2] = {f4{0.f, 0.f, 0.f, 0.f}, f4{0.f, 0.f, 0.f, 0.f}};
  const float C1 = 0.125f * 1.44269504089f;  // scale * log2(e)
  const int psb = wave * 1024;

  for (int kt = ks * 16; kt < ks * 16 + 16; ++kt) {
    __syncthreads();  // prior Kf/Vf reads (incl. bq prologue) complete
    // Kf: 512 chunks [kk:1][kg:2][qd:2][r16:4]
#pragma unroll
    for (int i = 0; i < 4; ++i) {
      int d = i * 128 + tid;
      int kk = d >> 8, kg = (d >> 6) & 3, qd = (d >> 4) & 3, r16 = d & 15;
      async_cp16(&Kf[d * 8],
                 qkv + (size_t)(b * SLEN + kt * 64 + kg * 16 + r16) * QLD +
                     EDIM + (kk * 4 + qd) * 8);
    }
    // Vf: 512 chunks [k4:1][ni:2][qd:2][r16:4]
#pragma unroll
    for (int i = 0; i < 4; ++i) {
      int d = i * 128 + tid;
      int k4 = d >> 8, ni = (d >> 6) & 3, qd = (d >> 4) & 3, r16 = d & 15;
      async_cp16(&Vf[d * 8],
                 vT + (size_t)(b * 64 + ni * 16 + r16) * SLEN + kt * 64 +
                     (k4 * 4 + qd) * 8);
    }
    __syncthreads();

    // per-32-key fused groups: QK -> softmax/pack -> wave-private Ps -> PV
#pragma unroll
    for (int k4 = 0; k4 < 2; ++k4) {
      f4 st[2][2];
#pragma unroll
      for (int j = 0; j < 2; ++j)
#pragma unroll
        for (int nt = 0; nt < 2; ++nt) st[j][nt] = f4{0.f, 0.f, 0.f, 0.f};
#pragma unroll
      for (int kk = 0; kk < 2; ++kk)
#pragma unroll
        for (int j = 0; j < 2; ++j) {
          bf8 ak = *(const bf8_a*)&Kf[((kk * 4 + k4 * 2 + j) * 64 + lane) * 8];
#pragma unroll
          for (int nt = 0; nt < 2; ++nt)
            st[j][nt] = __builtin_amdgcn_mfma_f32_16x16x32_bf16(
                ak, bq[nt][kk], st[j][nt], 0, 0, 0);
        }
#pragma unroll
      for (int nt = 0; nt < 2; ++nt)
#pragma unroll
        for (int j = 0; j < 2; ++j) {
          f4 pe;
          pe[0] = __builtin_amdgcn_exp2f(st[j][nt][0] * C1);
          pe[1] = __builtin_amdgcn_exp2f(st[j][nt][1] * C1);
          pe[2] = __builtin_amdgcn_exp2f(st[j][nt][2] * C1);
          pe[3] = __builtin_amdgcn_exp2f(st[j][nt][3] * C1);
          lr4[nt] += pe;
          uint2 pk;
          pk.x = pk2bf(pe[0], pe[1]);
          pk.y = pk2bf(pe[2], pe[3]);
          int qd2 = j * 2 + (quad >> 1);
          *(uint2_a*)&Ps[psb + ((nt * 4 + qd2) * 16 + l16) * 8 + (quad & 1) * 4] = pk;
        }
      asm volatile("" ::: "memory");  // Ps writes before PV reads (same wave)
      bf8 ap[2];
#pragma unroll
      for (int mt = 0; mt < 2; ++mt)
        ap[mt] = *(const bf8_a*)&Ps[psb + ((mt * 4 + quad) * 16 + l16) * 8];
#pragma unroll
      for (int ni = 0; ni < 4; ++ni) {
        bf8 bv = *(const bf8_a*)&Vf[((k4 * 4 + ni) * 64 + lane) * 8];
#pragma unroll
        for (int mt = 0; mt < 2; ++mt)
          acc_o[mt][ni] = __builtin_amdgcn_mfma_f32_16x16x32_bf16(
              ap[mt], bv, acc_o[mt][ni], 0, 0, 0);
      }
      asm volatile("" ::: "memory");  // PV reads before next group's Ps writes
    }
  }

  // store unnormalized partials: O bf16 [part][qrow][64], l fp32
  const size_t pbase = (size_t)(ks * 32 + bh) * 2048 + qt * 64;
  float ls[2];
#pragma unroll
  for (int nt = 0; nt < 2; ++nt) {
    float s = (lr4[nt][0] + lr4[nt][1]) + (lr4[nt][2] + lr4[nt][3]);
    s += __shfl_xor(s, 16, 64);
    s += __shfl_xor(s, 32, 64);
    ls[nt] = s;
    if (quad == 0) lpart[pbase + wave * 32 + nt * 16 + l16] = s;
  }
#pragma unroll
  for (int mt = 0; mt < 2; ++mt)
#pragma unroll
    for (int r = 0; r < 4; ++r) {
      size_t row = pbase + wave * 32 + mt * 16 + quad * 4 + r;
#pragma unroll
      for (int ni = 0; ni < 4; ++ni)
        Opart[row * 64 + ni * 16 + l16] = f2bf(acc_o[mt][ni][r]);
    }
}

// ---------------- out GEMM: A = (O0+O1)/(l0+l1) computed in staging ----------
// K-iteration it == head h (64 cols per head). d_out fp32.
__global__ __launch_bounds__(256) void gemm_out(
    const u16* __restrict__ Op, const float* __restrict__ lp,
    const u16* __restrict__ Bt, const float* __restrict__ bias,
    float* __restrict__ C) {
  __shared__ __align__(16) u16 As[64 * 64];
  __shared__ __align__(16) u16 Bs[128 * 64];
  const int K = 1024;
  const int tn0 = blockIdx.x * 128, tm0 = blockIdx.y * 64;
  const int tid = threadIdx.x, wave = tid >> 6, lane = tid & 63;
  const int quad = lane >> 4, l16 = lane & 15;
  const int wm = wave & 1, wn = wave >> 1;

  f4 acc[2][4];
#pragma unroll
  for (int i = 0; i < 2; ++i)
#pragma unroll
    for (int j = 0; j < 4; ++j) acc[i][j] = f4{0.f, 0.f, 0.f, 0.f};

  int aslot[2]; size_t obase[2]; int lbase[2];
#pragma unroll
  for (int i = 0; i < 2; ++i) {
    int s = i * 256 + tid, m = s >> 3, kc = s & 7, c = (kc - m) & 7;
    aslot[i] = s;
    int rowg = tm0 + m, b = rowg >> 11, qrow = rowg & 2047;
    obase[i] = (size_t)b * 2097152 + (size_t)qrow * 64 + c * 8;
    lbase[i] = b * 32768 + qrow;
  }
  int bslot[4]; size_t boff[4];
#pragma unroll
  for (int i = 0; i < 4; ++i) {
    int s = i * 256 + tid, n = s >> 3, kc = s & 7, c = (kc - n) & 7;
    bslot[i] = s; boff[i] = (size_t)(tn0 + n) * K + c * 8;
  }
  int ard[2][2], brd[4][2];
#pragma unroll
  for (int mi = 0; mi < 2; ++mi) {
    int m = wm * 32 + mi * 16 + l16;
#pragma unroll
    for (int kk = 0; kk < 2; ++kk)
      ard[mi][kk] = (m * 8 + (((kk * 4 + quad) + m) & 7)) * 8;
  }
#pragma unroll
  for (int ni = 0; ni < 4; ++ni) {
    int n = wn * 64 + ni * 16 + l16;
#pragma unroll
    for (int kk = 0; kk < 2; ++kk)
      brd[ni][kk] = (n * 8 + (((kk * 4 + quad) + n) & 7)) * 8;
  }

  for (int it = 0; it < 16; ++it) {
    // A: combine split-K partials + normalize, pre-barrier (regs only)
    uint4 staged[2];
#pragma unroll
    for (int i = 0; i < 2; ++i) {
      uint4 a0 = *(const uint4_a*)(Op + obase[i] + (size_t)it * 131072);
      uint4 a1 = *(const uint4_a*)(Op + obase[i] + (size_t)it * 131072 + 4194304);
      float l0 = lp[lbase[i] + it * 2048];
      float l1 = lp[lbase[i] + 65536 + it * 2048];
      float inv = 1.f / (l0 + l1);
      const u16* pa = (const u16*)&a0;
      const u16* pb = (const u16*)&a1;
      u16 tmp[8];
#pragma unroll
      for (int j = 0; j < 8; ++j)
        tmp[j] = f2bf((bf2f(pa[j]) + bf2f(pb[j])) * inv);
      staged[i] = *(const uint4_a*)tmp;
    }
    __syncthreads();  // prior frag reads done
#pragma unroll
    for (int i = 0; i < 2; ++i) *(uint4_a*)&As[aslot[i] * 8] = staged[i];
#pragma unroll
    for (int i = 0; i < 4; ++i)
      async_cp16(&Bs[bslot[i] * 8], Bt + boff[i] + (size_t)it * 64);
    __syncthreads();
#pragma unroll
    for (int kk = 0; kk < 2; ++kk) {
      bf8 af[2], bfr[4];
#pragma unroll
      for (int mi = 0; mi < 2; ++mi) af[mi] = *(const bf8_a*)&As[ard[mi][kk]];
#pragma unroll
      for (int ni = 0; ni < 4; ++ni) bfr[ni] = *(const bf8_a*)&Bs[brd[ni][kk]];
#pragma unroll
      for (int mi = 0; mi < 2; ++mi)
#pragma unroll
        for (int ni = 0; ni < 4; ++ni)
          acc[mi][ni] = __builtin_amdgcn_mfma_f32_16x16x32_bf16(
              af[mi], bfr[ni], acc[mi][ni], 0, 0, 0);
    }
  }

  float bv[4];
#pragma unroll
  for (int ni = 0; ni < 4; ++ni) bv[ni] = bias[tn0 + wn * 64 + ni * 16 + l16];
#pragma unroll
  for (int mi = 0; mi < 2; ++mi) {
    int row0 = tm0 + wm * 32 + mi * 16 + quad * 4;
#pragma unroll
    for (int ni = 0; ni < 4; ++ni) {
      int col = tn0 + wn * 64 + ni * 16 + l16;
#pragma unroll
      for (int r = 0; r < 4; ++r)
        C[(size_t)(row0 + r) * 1024 + col] = acc[mi][ni][r] + bv[ni];
    }
  }
}

// ---------------- host ------------------------------------------------------
extern "C" void kernel_launch(void* const* d_in, const int* in_sizes, int n_in,
                              void* d_out, int out_size, void* d_ws, size_t ws_size,
                              hipStream_t stream) {
  const float* x  = (const float*)d_in[0];
  const float* wq = (const float*)d_in[1];
  const float* bq = (const float*)d_in[2];
  const float* wk = (const float*)d_in[3];
  const float* bk = (const float*)d_in[4];
  const float* wv = (const float*)d_in[5];
  const float* bv = (const float*)d_in[6];
  const float* wo = (const float*)d_in[7];
  const float* bo = (const float*)d_in[8];

  char* ws = (char*)d_ws;
  size_t off = 0;
  auto carve = [&](size_t bytes) {
    void* p = ws + off;
    off = (off + bytes + 255) & ~(size_t)255;
    return p;
  };
  u16* wT      = (u16*)carve((size_t)1152 * 1024 * 2);  // packed [wq|wk|wv]^T
  u16* woT     = (u16*)carve((size_t)1024 * 1024 * 2);
  float* bQKV  = (float*)carve(1152 * 4);
  float* bOut  = (float*)carve(1024 * 4);
  u16* qkvb    = (u16*)carve((size_t)4096 * QLD * 2);
  u16* vTb     = (u16*)carve((size_t)2 * 64 * SLEN * 2);
  u16* Opart   = (u16*)carve((size_t)2 * 32 * 2048 * 64 * 2);  // 16.8 MB
  float* lpart = (float*)carve((size_t)2 * 32 * 2048 * 4);     // 0.5 MB

  // prep: weight transposes + bias
  prep_w<<<dim3(16, 35), 256, 0, stream>>>(wq, wk, wv, wo, bq, bk, bv, bo,
                                           wT, woT, bQKV, bOut);

  // QKV projection (x converted in staging) + fused V-transpose
  gemm_qkv<<<dim3(9, 64), 256, 0, stream>>>(x, wT, bQKV, qkvb, vTb);

  // flash attention, split-K over key halves
  attn_kernel<<<dim3(32, 32, 2), 128, 0, stream>>>(qkvb, vTb, Opart, lpart);

  // output projection (split-K combine fused into A-staging) -> d_out fp32
  gemm_out<<<dim3(8, 64), 256, 0, stream>>>(Opart, lpart, woT, bOut,
                                            (float*)d_out);
}